// Round 12
// baseline (134.707 us; speedup 1.0000x reference)
//
#include <hip/hip_runtime.h>
#include <hip/hip_bf16.h>

// spatial_attention: out = weights @ P1 + P2
//   P1 = H W1^T ; P2 = H W2^T + bias  (same A-rows -> computed together in kA)
//   Domain uniform (runtime-verified) -> weights fast path: w = relu(dval - dist).
//   K0 : Wbf = bf16(W); k0_check -> {dval, uniform}
//   kA : EVEN blocks: dual GEMM -> P1T (transposed bf16) + P2 (row-major bf16)
//        ODD  blocks: weights -> weBuf (pre-scaled bf16)
//        (parity interleave => each CU hosts one of each; streams overlap)
//   k2b: out = weBuf @ P1T + P2. K=256 pure GEMM at BW roofline (R10-proven).
// Workspace: Wbf 512KB @0 ; flag @512KB ; P1T 32MB @1MB ; P2 32MB @33MB ; weBuf 32MB @65MB

typedef __attribute__((ext_vector_type(4))) float  f32x4;
typedef __attribute__((ext_vector_type(8))) short  bf16x8;
typedef __attribute__((ext_vector_type(4))) short  bf16x4;

#define EPSC 1e-14f

__device__ __forceinline__ short f2bf(float v) {
  __hip_bfloat16 h = __float2bfloat16(v);
  return *reinterpret_cast<short*>(&h);
}
__device__ __forceinline__ float bf2f(unsigned short u) {
  union { unsigned int i; float f; } c; c.i = ((unsigned int)u) << 16; return c.f;
}
__device__ __forceinline__ void gload16(const void* g, void* l) {
  __builtin_amdgcn_global_load_lds(
      (const __attribute__((address_space(1))) void*)g,
      (__attribute__((address_space(3))) void*)l, 16, 0, 0);
}

// ---------------- K0: W fp32 -> bf16 ----------------
__global__ void k0_pack(const float* __restrict__ W, short* __restrict__ Wbf) {
  int idx = blockIdx.x * 256 + threadIdx.x;
  f32x4 v = *(const f32x4*)(W + (size_t)idx * 4);
  bf16x4 pk;
  pk[0] = f2bf(v[0]); pk[1] = f2bf(v[1]); pk[2] = f2bf(v[2]); pk[3] = f2bf(v[3]);
  *(bf16x4*)(Wbf + (size_t)idx * 4) = pk;
}

// ---------------- K0b: domain uniformity check ----------------
__global__ void k0_check(const float* __restrict__ domain, float* __restrict__ flag) {
  __shared__ int s_ok[4];
  const int t = threadIdx.x;
  float v0 = domain[0];
  bool ok = true;
  for (int x = t; x < 72 * 72; x += 256) ok = ok && (domain[x] == v0);
  unsigned long long m = __ballot(ok);
  if ((t & 63) == 0) s_ok[t >> 6] = (m == ~0ull) ? 1 : 0;
  __syncthreads();
  if (t == 0) {
    flag[0] = v0;
    flag[1] = (s_ok[0] && s_ok[1] && s_ok[2] && s_ok[3]) ? 1.f : 0.f;
  }
}

// ---------------- kA: grid 2048, block 512, LDS 70656 ----------------
// EVEN blocks (bid = x>>1): dual-GEMM. sA = 64 H-rows staged ONCE (shared by both passes).
//   pass 0: B = W[:, :256] -> P1T[b][d][j] bf16 ; pass 1: B = W[:, 256:] -> P2 + bias
// ODD blocks: weights, wave-per-row style (8 waves x 8 rows = 64 rows).
__global__ __launch_bounds__(512) void kA(
    const float* __restrict__ H, const short* __restrict__ Wbf,
    const float* __restrict__ bias, const float* __restrict__ dist,
    const float* __restrict__ bear, const float* __restrict__ head,
    const float* __restrict__ seqmask, const float* __restrict__ domain,
    const float* __restrict__ uflag,
    short* __restrict__ P1T, short* __restrict__ P2, short* __restrict__ weBuf) {
  extern __shared__ char sm[];
  const int t = threadIdx.x;
  const int bid = blockIdx.x >> 1;

  if ((blockIdx.x & 1) == 0) {
    // ================= dual-GEMM part =================
    char* sA = sm;                       // 64 rows x 256 k bf16, 528B stride
    char* sB = sm + 33792;               // 256 d x 64 k bf16, 144B stride
    const int n0 = bid * 64;
    const int b  = n0 >> 8;
    const int jb = n0 & 255;

    // stage sA once (fp32 -> bf16)
    #pragma unroll
    for (int p = 0; p < 4; ++p) {
      int z = t + 512 * p;               // 0..2047 : j = z>>5, seg = z&31
      int j = z >> 5, seg = z & 31;
      const float* src = H + (size_t)(n0 + j) * 256 + seg * 8;
      f32x4 h0 = *(const f32x4*)src;
      f32x4 h1 = *(const f32x4*)(src + 4);
      bf16x8 pk;
      pk[0] = f2bf(h0[0]); pk[1] = f2bf(h0[1]); pk[2] = f2bf(h0[2]); pk[3] = f2bf(h0[3]);
      pk[4] = f2bf(h1[0]); pk[5] = f2bf(h1[1]); pk[6] = f2bf(h1[2]); pk[7] = f2bf(h1[3]);
      *(bf16x8*)(sA + j * 528 + seg * 16) = pk;
    }

    const int wid = t >> 6, l = t & 63;
    const int wn = wid >> 2, wc = wid & 3;     // 2 x 32 rows, 4 x 64 d
    const int lr = l & 15, lg = l >> 4;

    #pragma unroll
    for (int pass = 0; pass < 2; ++pass) {
      f32x4 acc[2][4] = {};
      for (int kk = 0; kk < 256; kk += 64) {
        __syncthreads();                 // prev chunk consumed (and sA ready at first)
        #pragma unroll
        for (int p = 0; p < 4; ++p) {
          int z = t + 512 * p;           // d = z>>3, s = z&7
          int d = z >> 3, s = z & 7;
          bf16x8 v = *(const bf16x8*)(Wbf + (size_t)d * 512 + pass * 256 + kk + s * 8);
          *(bf16x8*)(sB + d * 144 + s * 16) = v;
        }
        __syncthreads();
        #pragma unroll
        for (int sub = 0; sub < 2; ++sub) {
          bf16x8 a[2], bb[4];
          #pragma unroll
          for (int m = 0; m < 2; ++m) {
            int row = wn * 32 + m * 16 + lr;
            a[m] = *(const bf16x8*)(sA + row * 528 + (kk + sub * 32 + lg * 8) * 2);
          }
          #pragma unroll
          for (int f = 0; f < 4; ++f) {
            int d = wc * 64 + f * 16 + lr;
            bb[f] = *(const bf16x8*)(sB + d * 144 + sub * 64 + lg * 16);
          }
          #pragma unroll
          for (int m = 0; m < 2; ++m) {
            #pragma unroll
            for (int f = 0; f < 4; ++f)
              acc[m][f] = __builtin_amdgcn_mfma_f32_16x16x32_bf16(a[m], bb[f], acc[m][f], 0, 0, 0);
          }
        }
      }
      // epilogue
      if (pass == 0) {
        #pragma unroll
        for (int m = 0; m < 2; ++m) {
          int jl = wn * 32 + m * 16 + lg * 4;
          #pragma unroll
          for (int f = 0; f < 4; ++f) {
            int d = wc * 64 + f * 16 + lr;
            f32x4 v = acc[m][f];
            bf16x4 pk;
            pk[0] = f2bf(v[0]); pk[1] = f2bf(v[1]); pk[2] = f2bf(v[2]); pk[3] = f2bf(v[3]);
            *(bf16x4*)(P1T + (size_t)b * 65536 + (size_t)d * 256 + jb + jl) = pk;
          }
        }
      } else {
        #pragma unroll
        for (int m = 0; m < 2; ++m) {
          int jl = wn * 32 + m * 16 + lg * 4;
          #pragma unroll
          for (int f = 0; f < 4; ++f) {
            int d = wc * 64 + f * 16 + lr;
            float bs = bias[d];
            f32x4 v = acc[m][f];
            #pragma unroll
            for (int r = 0; r < 4; ++r)
              P2[(size_t)b * 65536 + (size_t)(jb + jl + r) * 256 + d] = f2bf(v[r] + bs);
          }
        }
      }
    }
  } else {
    // ================= weights part =================
    float* sMask = (float*)sm;
    const int b  = bid >> 2;
    const int i0 = (bid & 3) * 64;
    if (t < 256) sMask[t] = seqmask[b * 256 + t];
    __syncthreads();

    const int w = t >> 6, l = t & 63;
    const int j0 = l * 4;
    const float dval = uflag[0];
    const bool  uni  = uflag[1] != 0.f;
    const f32x4 mj = *(const f32x4*)(sMask + j0);

    f32x4 dv[8];
    #pragma unroll
    for (int rr = 0; rr < 8; ++rr) {
      int i = i0 + w * 8 + rr;
      dv[rr] = *(const f32x4*)(dist + ((size_t)b * 256 + i) * 256 + j0);
    }

    #pragma unroll
    for (int rr = 0; rr < 8; ++rr) {
      const int i = i0 + w * 8 + rr;
      const float mI = sMask[i];
      const size_t base = ((size_t)b * 256 + i) * 256;
      float ev[4];
      float rs = 0.f;
      if (uni) {
        #pragma unroll
        for (int e = 0; e < 4; ++e) {
          float wv = fmaxf(dval - dv[rr][e], 0.f);
          bool valid = (i != j0 + e) && (mI != 0.f) && (mj[e] != 0.f);
          float ex = (wv > 0.f) ? __expf(wv) : 0.f;
          ex = valid ? ex : 0.f;
          rs += ex;
          ev[e] = valid ? (ex + EPSC) : 0.f;
        }
      } else {
        f32x4 bv = *(const f32x4*)(bear + base + j0);
        f32x4 hv = *(const f32x4*)(head + base + j0);
        #pragma unroll
        for (int e = 0; e < 4; ++e) {
          float f1 = fminf(fmaxf(floorf((hv[e] + 2.5f) * 0.2f), 0.f), 71.f);
          float f2 = fminf(fmaxf(floorf((bv[e] + 2.5f) * 0.2f), 0.f), 71.f);
          float wv = fmaxf(domain[(int)(f1 * 72.f + f2)] - dv[rr][e], 0.f);
          bool valid = (i != j0 + e) && (mI != 0.f) && (mj[e] != 0.f);
          float ex = (wv > 0.f) ? __expf(wv) : 0.f;
          ex = valid ? ex : 0.f;
          rs += ex;
          ev[e] = valid ? (ex + EPSC) : 0.f;
        }
      }
      rs += __shfl_xor(rs, 1, 64);
      rs += __shfl_xor(rs, 2, 64);
      rs += __shfl_xor(rs, 4, 64);
      rs += __shfl_xor(rs, 8, 64);
      rs += __shfl_xor(rs, 16, 64);
      rs += __shfl_xor(rs, 32, 64);
      const float scale = 1.0f / (rs + 257.0f * EPSC);
      bf16x4 pk;
      pk[0] = f2bf(ev[0] * scale); pk[1] = f2bf(ev[1] * scale);
      pk[2] = f2bf(ev[2] * scale); pk[3] = f2bf(ev[3] * scale);
      *(bf16x4*)(weBuf + base + j0) = pk;
    }
  }
}

// ---------------- K2b: out = weBuf @ P1T + P2, K=256 (BW-roofline, R10-proven) ----------------
__global__ __launch_bounds__(512) void k2b_gemm(
    const short* __restrict__ weBuf, const short* __restrict__ P1T,
    const short* __restrict__ P2, float* __restrict__ out) {
  extern __shared__ char sm[];
  char* sB = sm;
  const int t = threadIdx.x;
  const int x = blockIdx.x;
  const int blk = (x & 7) * 128 + (x >> 3);    // bijective: 1024 = 8*128
  const int b  = blk >> 2;
  const int i0 = (blk & 3) * 64;

  const int wid = t >> 6, l = t & 63;
  const int lr = l & 15, lg = l >> 4;
  const int wr = wid & 3, wc = wid >> 2;
  const int r3 = l >> 3, sl = l & 7;
  const int sswz = (sl ^ r3) * 8;
  const int sw = (lr & 7) << 4;

  const short* __restrict__ P1b = P1T + (size_t)b * 65536;
  const int i = i0 + wr * 16 + lr;
  const size_t abase = ((size_t)b * 256 + i) * 256;

  f32x4 acc[8] = {};

  for (int c = 0; c < 4; ++c) {
    const int kk = c * 64;
    #pragma unroll
    for (int p = 0; p < 4; ++p) {
      int dd = wid * 8 + r3 + 64 * p;
      gload16(P1b + (size_t)dd * 256 + kk + sswz, sB + (wid * 8 + 64 * p) * 128);
    }
    __syncthreads();
    #pragma unroll
    for (int sub = 0; sub < 2; ++sub) {
      bf16x8 av = *(const bf16x8*)(weBuf + abase + kk + sub * 32 + lg * 8);
      #pragma unroll
      for (int n = 0; n < 8; ++n) {
        const int d = wc * 128 + n * 16 + lr;
        bf16x8 bb = *(const bf16x8*)(sB + d * 128 + ((sub * 64 + lg * 16) ^ sw));
        acc[n] = __builtin_amdgcn_mfma_f32_16x16x32_bf16(av, bb, acc[n], 0, 0, 0);
      }
    }
    __syncthreads();
  }

  #pragma unroll
  for (int n = 0; n < 8; ++n) {
    const int d = wc * 128 + n * 16 + lr;
    #pragma unroll
    for (int r = 0; r < 4; ++r) {
      const int row = i0 + wr * 16 + lg * 4 + r;
      const size_t off = ((size_t)b * 256 + row) * 256 + d;
      out[off] = acc[n][r] + bf2f((unsigned short)P2[off]);
    }
  }
}

extern "C" void kernel_launch(void* const* d_in, const int* in_sizes, int n_in,
                              void* d_out, int out_size, void* d_ws, size_t ws_size,
                              hipStream_t stream) {
  const float* hidden  = (const float*)d_in[0];
  const float* dist    = (const float*)d_in[1];
  const float* bear    = (const float*)d_in[2];
  const float* head    = (const float*)d_in[3];
  const float* seqmask = (const float*)d_in[4];
  const float* domain  = (const float*)d_in[5];
  const float* W       = (const float*)d_in[6];
  const float* bias    = (const float*)d_in[7];
  float* out = (float*)d_out;

  char* ws = (char*)d_ws;
  short* Wbf   = (short*)ws;                                 // 512 KB
  float* flag  = (float*)(ws + 524288);                      // 2 floats
  short* P1T   = (short*)(ws + (1u << 20));                  // 32 MB
  short* P2    = (short*)(ws + (1u << 20) + (32u << 20));    // 32 MB
  short* weBuf = (short*)(ws + (1u << 20) + (64u << 20));    // 32 MB

  k0_pack<<<128, 256, 0, stream>>>(W, Wbf);
  k0_check<<<1, 256, 0, stream>>>(domain, flag);
  kA<<<2048, 512, 70656, stream>>>(hidden, Wbf, bias, dist, bear, head,
                                   seqmask, domain, flag, P1T, P2, weBuf);
  k2b_gemm<<<1024, 512, 32768, stream>>>(weBuf, P1T, P2, out);
}

// Round 13
// 122.648 us; speedup vs baseline: 1.0983x; 1.0983x over previous
//
#include <hip/hip_runtime.h>
#include <hip/hip_bf16.h>

// spatial_attention: out = weights @ P1 + P2
//   P1 = H W1^T ; P2 = H W2^T + bias  (same A-rows -> one dual-GEMM kernel)
//   Domain uniform (runtime-verified) -> weights fast path: w = relu(dval - dist).
//   SEPARATE kernels (merging measured worse in R10/R11):
//   K0    : Wbf = bf16(W); k0_check -> {dval, uniform}
//   k1dual: grid 1024, 64 H-rows/block staged once -> P1T (transposed) + P2 (+bias)
//   k2a   : grid 2048, wave-per-row weights -> weBuf (pre-scaled bf16), tiny LDS
//   k2b   : out = weBuf @ P1T + P2, K=256, gload16+swizzle (R10 BW-roofline form)
// Workspace: Wbf 512KB @0 ; flag @512KB ; P1T 32MB @1MB ; P2 32MB @33MB ; weBuf 32MB @65MB

typedef __attribute__((ext_vector_type(4))) float  f32x4;
typedef __attribute__((ext_vector_type(8))) short  bf16x8;
typedef __attribute__((ext_vector_type(4))) short  bf16x4;

#define EPSC 1e-14f

__device__ __forceinline__ short f2bf(float v) {
  __hip_bfloat16 h = __float2bfloat16(v);
  return *reinterpret_cast<short*>(&h);
}
__device__ __forceinline__ float bf2f(unsigned short u) {
  union { unsigned int i; float f; } c; c.i = ((unsigned int)u) << 16; return c.f;
}
__device__ __forceinline__ void gload16(const void* g, void* l) {
  __builtin_amdgcn_global_load_lds(
      (const __attribute__((address_space(1))) void*)g,
      (__attribute__((address_space(3))) void*)l, 16, 0, 0);
}

// ---------------- K0: W fp32 -> bf16 ----------------
__global__ void k0_pack(const float* __restrict__ W, short* __restrict__ Wbf) {
  int idx = blockIdx.x * 256 + threadIdx.x;
  f32x4 v = *(const f32x4*)(W + (size_t)idx * 4);
  bf16x4 pk;
  pk[0] = f2bf(v[0]); pk[1] = f2bf(v[1]); pk[2] = f2bf(v[2]); pk[3] = f2bf(v[3]);
  *(bf16x4*)(Wbf + (size_t)idx * 4) = pk;
}

// ---------------- K0b: domain uniformity check ----------------
__global__ void k0_check(const float* __restrict__ domain, float* __restrict__ flag) {
  __shared__ int s_ok[4];
  const int t = threadIdx.x;
  float v0 = domain[0];
  bool ok = true;
  for (int x = t; x < 72 * 72; x += 256) ok = ok && (domain[x] == v0);
  unsigned long long m = __ballot(ok);
  if ((t & 63) == 0) s_ok[t >> 6] = (m == ~0ull) ? 1 : 0;
  __syncthreads();
  if (t == 0) {
    flag[0] = v0;
    flag[1] = (s_ok[0] && s_ok[1] && s_ok[2] && s_ok[3]) ? 1.f : 0.f;
  }
}

// ---------------- k1dual: grid 1024 (64 H-rows), block 512, LDS 70656 ----------------
// sA = 64 rows x 256 k staged ONCE; pass 0: W1 -> P1T (transposed); pass 1: W2 -> P2 + bias.
__global__ __launch_bounds__(512) void k1dual(
    const float* __restrict__ H, const short* __restrict__ Wbf,
    const float* __restrict__ bias,
    short* __restrict__ P1T, short* __restrict__ P2) {
  extern __shared__ char sm[];
  char* sA = sm;                       // 64 rows x 256 k bf16, 528B stride
  char* sB = sm + 33792;               // 256 d x 64 k bf16, 144B stride
  const int t  = threadIdx.x;
  const int n0 = blockIdx.x * 64;
  const int b  = n0 >> 8;
  const int jb = n0 & 255;

  // stage sA once (fp32 -> bf16)
  #pragma unroll
  for (int p = 0; p < 4; ++p) {
    int z = t + 512 * p;               // 0..2047 : j = z>>5, seg = z&31
    int j = z >> 5, seg = z & 31;
    const float* src = H + (size_t)(n0 + j) * 256 + seg * 8;
    f32x4 h0 = *(const f32x4*)src;
    f32x4 h1 = *(const f32x4*)(src + 4);
    bf16x8 pk;
    pk[0] = f2bf(h0[0]); pk[1] = f2bf(h0[1]); pk[2] = f2bf(h0[2]); pk[3] = f2bf(h0[3]);
    pk[4] = f2bf(h1[0]); pk[5] = f2bf(h1[1]); pk[6] = f2bf(h1[2]); pk[7] = f2bf(h1[3]);
    *(bf16x8*)(sA + j * 528 + seg * 16) = pk;
  }

  const int wid = t >> 6, l = t & 63;
  const int wn = wid >> 2, wc = wid & 3;     // 2 x 32 rows, 4 x 64 d
  const int lr = l & 15, lg = l >> 4;

  #pragma unroll
  for (int pass = 0; pass < 2; ++pass) {
    f32x4 acc[2][4] = {};
    for (int kk = 0; kk < 256; kk += 64) {
      __syncthreads();                 // prev chunk consumed (and sA ready at first)
      #pragma unroll
      for (int p = 0; p < 4; ++p) {
        int z = t + 512 * p;           // d = z>>3, s = z&7
        int d = z >> 3, s = z & 7;
        bf16x8 v = *(const bf16x8*)(Wbf + (size_t)d * 512 + pass * 256 + kk + s * 8);
        *(bf16x8*)(sB + d * 144 + s * 16) = v;
      }
      __syncthreads();
      #pragma unroll
      for (int sub = 0; sub < 2; ++sub) {
        bf16x8 a[2], bb[4];
        #pragma unroll
        for (int m = 0; m < 2; ++m) {
          int row = wn * 32 + m * 16 + lr;
          a[m] = *(const bf16x8*)(sA + row * 528 + (kk + sub * 32 + lg * 8) * 2);
        }
        #pragma unroll
        for (int f = 0; f < 4; ++f) {
          int d = wc * 64 + f * 16 + lr;
          bb[f] = *(const bf16x8*)(sB + d * 144 + sub * 64 + lg * 16);
        }
        #pragma unroll
        for (int m = 0; m < 2; ++m) {
          #pragma unroll
          for (int f = 0; f < 4; ++f)
            acc[m][f] = __builtin_amdgcn_mfma_f32_16x16x32_bf16(a[m], bb[f], acc[m][f], 0, 0, 0);
        }
      }
    }
    // epilogue
    if (pass == 0) {
      #pragma unroll
      for (int m = 0; m < 2; ++m) {
        int jl = wn * 32 + m * 16 + lg * 4;
        #pragma unroll
        for (int f = 0; f < 4; ++f) {
          int d = wc * 64 + f * 16 + lr;
          f32x4 v = acc[m][f];
          bf16x4 pk;
          pk[0] = f2bf(v[0]); pk[1] = f2bf(v[1]); pk[2] = f2bf(v[2]); pk[3] = f2bf(v[3]);
          *(bf16x4*)(P1T + (size_t)b * 65536 + (size_t)d * 256 + jb + jl) = pk;
        }
      }
    } else {
      #pragma unroll
      for (int m = 0; m < 2; ++m) {
        int jl = wn * 32 + m * 16 + lg * 4;
        #pragma unroll
        for (int f = 0; f < 4; ++f) {
          int d = wc * 64 + f * 16 + lr;
          float bs = bias[d];
          f32x4 v = acc[m][f];
          #pragma unroll
          for (int r = 0; r < 4; ++r)
            P2[(size_t)b * 65536 + (size_t)(jb + jl + r) * 256 + d] = f2bf(v[r] + bs);
        }
      }
    }
  }
}

// ---------------- k2a: pre-scaled weights, wave-per-row (R9-proven) ----------------
// grid 2048 (b = blk>>3, i0 = (blk&7)*32), block 256 = 4 waves; wave does 8 rows.
__global__ __launch_bounds__(256) void k2a_weights(
    const float* __restrict__ dist, const float* __restrict__ bear,
    const float* __restrict__ head, const float* __restrict__ seqmask,
    const float* __restrict__ domain, const float* __restrict__ uflag,
    short* __restrict__ weBuf) {
  __shared__ float sMask[256];
  const int t = threadIdx.x;
  const int b = blockIdx.x >> 3;
  const int i0 = (blockIdx.x & 7) * 32;
  if (t < 256) sMask[t] = seqmask[b * 256 + t];
  __syncthreads();

  const int w = t >> 6, l = t & 63;
  const int j0 = l * 4;
  const float dval = uflag[0];
  const bool  uni  = uflag[1] != 0.f;
  const f32x4 mj = *(const f32x4*)(sMask + j0);

  f32x4 dv[8];
  #pragma unroll
  for (int rr = 0; rr < 8; ++rr) {
    int i = i0 + w * 8 + rr;
    dv[rr] = *(const f32x4*)(dist + ((size_t)b * 256 + i) * 256 + j0);
  }

  #pragma unroll
  for (int rr = 0; rr < 8; ++rr) {
    const int i = i0 + w * 8 + rr;
    const float mI = sMask[i];
    const size_t base = ((size_t)b * 256 + i) * 256;
    float ev[4];
    float rs = 0.f;
    if (uni) {
      #pragma unroll
      for (int e = 0; e < 4; ++e) {
        float wv = fmaxf(dval - dv[rr][e], 0.f);
        bool valid = (i != j0 + e) && (mI != 0.f) && (mj[e] != 0.f);
        float ex = (wv > 0.f) ? __expf(wv) : 0.f;
        ex = valid ? ex : 0.f;
        rs += ex;
        ev[e] = valid ? (ex + EPSC) : 0.f;
      }
    } else {
      f32x4 bv = *(const f32x4*)(bear + base + j0);
      f32x4 hv = *(const f32x4*)(head + base + j0);
      #pragma unroll
      for (int e = 0; e < 4; ++e) {
        float f1 = fminf(fmaxf(floorf((hv[e] + 2.5f) * 0.2f), 0.f), 71.f);
        float f2 = fminf(fmaxf(floorf((bv[e] + 2.5f) * 0.2f), 0.f), 71.f);
        float wv = fmaxf(domain[(int)(f1 * 72.f + f2)] - dv[rr][e], 0.f);
        bool valid = (i != j0 + e) && (mI != 0.f) && (mj[e] != 0.f);
        float ex = (wv > 0.f) ? __expf(wv) : 0.f;
        ex = valid ? ex : 0.f;
        rs += ex;
        ev[e] = valid ? (ex + EPSC) : 0.f;
      }
    }
    rs += __shfl_xor(rs, 1, 64);
    rs += __shfl_xor(rs, 2, 64);
    rs += __shfl_xor(rs, 4, 64);
    rs += __shfl_xor(rs, 8, 64);
    rs += __shfl_xor(rs, 16, 64);
    rs += __shfl_xor(rs, 32, 64);
    const float scale = 1.0f / (rs + 257.0f * EPSC);
    bf16x4 pk;
    pk[0] = f2bf(ev[0] * scale); pk[1] = f2bf(ev[1] * scale);
    pk[2] = f2bf(ev[2] * scale); pk[3] = f2bf(ev[3] * scale);
    *(bf16x4*)(weBuf + base + j0) = pk;
  }
}

// ---------------- k2b: out = weBuf @ P1T + P2, K=256 (BW-roofline, R10-proven) ----------------
__global__ __launch_bounds__(512) void k2b_gemm(
    const short* __restrict__ weBuf, const short* __restrict__ P1T,
    const short* __restrict__ P2, float* __restrict__ out) {
  extern __shared__ char sm[];
  char* sB = sm;
  const int t = threadIdx.x;
  const int x = blockIdx.x;
  const int blk = (x & 7) * 128 + (x >> 3);    // bijective: 1024 = 8*128
  const int b  = blk >> 2;
  const int i0 = (blk & 3) * 64;

  const int wid = t >> 6, l = t & 63;
  const int lr = l & 15, lg = l >> 4;
  const int wr = wid & 3, wc = wid >> 2;
  const int r3 = l >> 3, sl = l & 7;
  const int sswz = (sl ^ r3) * 8;
  const int sw = (lr & 7) << 4;

  const short* __restrict__ P1b = P1T + (size_t)b * 65536;
  const int i = i0 + wr * 16 + lr;
  const size_t abase = ((size_t)b * 256 + i) * 256;

  f32x4 acc[8] = {};

  for (int c = 0; c < 4; ++c) {
    const int kk = c * 64;
    #pragma unroll
    for (int p = 0; p < 4; ++p) {
      int dd = wid * 8 + r3 + 64 * p;
      gload16(P1b + (size_t)dd * 256 + kk + sswz, sB + (wid * 8 + 64 * p) * 128);
    }
    __syncthreads();
    #pragma unroll
    for (int sub = 0; sub < 2; ++sub) {
      bf16x8 av = *(const bf16x8*)(weBuf + abase + kk + sub * 32 + lg * 8);
      #pragma unroll
      for (int n = 0; n < 8; ++n) {
        const int d = wc * 128 + n * 16 + lr;
        bf16x8 bb = *(const bf16x8*)(sB + d * 128 + ((sub * 64 + lg * 16) ^ sw));
        acc[n] = __builtin_amdgcn_mfma_f32_16x16x32_bf16(av, bb, acc[n], 0, 0, 0);
      }
    }
    __syncthreads();
  }

  #pragma unroll
  for (int n = 0; n < 8; ++n) {
    const int d = wc * 128 + n * 16 + lr;
    #pragma unroll
    for (int r = 0; r < 4; ++r) {
      const int row = i0 + wr * 16 + lg * 4 + r;
      const size_t off = ((size_t)b * 256 + row) * 256 + d;
      out[off] = acc[n][r] + bf2f((unsigned short)P2[off]);
    }
  }
}

extern "C" void kernel_launch(void* const* d_in, const int* in_sizes, int n_in,
                              void* d_out, int out_size, void* d_ws, size_t ws_size,
                              hipStream_t stream) {
  const float* hidden  = (const float*)d_in[0];
  const float* dist    = (const float*)d_in[1];
  const float* bear    = (const float*)d_in[2];
  const float* head    = (const float*)d_in[3];
  const float* seqmask = (const float*)d_in[4];
  const float* domain  = (const float*)d_in[5];
  const float* W       = (const float*)d_in[6];
  const float* bias    = (const float*)d_in[7];
  float* out = (float*)d_out;

  char* ws = (char*)d_ws;
  short* Wbf   = (short*)ws;                                 // 512 KB
  float* flag  = (float*)(ws + 524288);                      // 2 floats
  short* P1T   = (short*)(ws + (1u << 20));                  // 32 MB
  short* P2    = (short*)(ws + (1u << 20) + (32u << 20));    // 32 MB
  short* weBuf = (short*)(ws + (1u << 20) + (64u << 20));    // 32 MB

  k0_pack<<<128, 256, 0, stream>>>(W, Wbf);
  k0_check<<<1, 256, 0, stream>>>(domain, flag);
  k2a_weights<<<2048, 256, 0, stream>>>(dist, bear, head, seqmask, domain, flag, weBuf);
  k1dual<<<1024, 512, 70656, stream>>>(hidden, Wbf, bias, P1T, P2);
  k2b_gemm<<<1024, 512, 32768, stream>>>(weBuf, P1T, P2, out);
}

// Round 14
// 114.969 us; speedup vs baseline: 1.1717x; 1.0668x over previous
//
#include <hip/hip_runtime.h>
#include <hip/hip_bf16.h>

// spatial_attention: out = weights @ (H W1^T) + H @ W2^T + bias
//   Domain uniform (runtime-verified) -> weights fast path: w = relu(dval - dist).
//   All GEMMs use the R10-proven skeleton: gload16 B-staging (linear dest +
//   pre-swizzled source + XOR reads), 64-row blocks, 8 waves (16r x 128d, acc[8]),
//   4 blocks/CU, XCD-swizzled grid.
//   K0    : Wbf = bf16(W); k0_check -> {dval, uniform}
//   k2a   : weights -> weBuf (pre-scaled bf16), wave-per-row, tiny LDS
//   k1_p1t: P1T[b][d][j] = bf16((H W1^T)^T), A=H per-thread cvt, B=W1 gload16
//   k2b   : out = weBuf @ P1T (chunks 0-3) + bf16(H) @ W2 (chunks 4-7) + bias
// Workspace: Wbf 512KB @0 ; flag @512KB ; P1T 32MB @1MB ; weBuf 32MB @33MB

typedef __attribute__((ext_vector_type(4))) float  f32x4;
typedef __attribute__((ext_vector_type(8))) short  bf16x8;
typedef __attribute__((ext_vector_type(4))) short  bf16x4;

#define EPSC 1e-14f

__device__ __forceinline__ short f2bf(float v) {
  __hip_bfloat16 h = __float2bfloat16(v);
  return *reinterpret_cast<short*>(&h);
}
__device__ __forceinline__ void gload16(const void* g, void* l) {
  __builtin_amdgcn_global_load_lds(
      (const __attribute__((address_space(1))) void*)g,
      (__attribute__((address_space(3))) void*)l, 16, 0, 0);
}
__device__ __forceinline__ bf16x8 cvt8(const float* p) {
  f32x4 a = *(const f32x4*)p;
  f32x4 b = *(const f32x4*)(p + 4);
  bf16x8 r;
  r[0] = f2bf(a[0]); r[1] = f2bf(a[1]); r[2] = f2bf(a[2]); r[3] = f2bf(a[3]);
  r[4] = f2bf(b[0]); r[5] = f2bf(b[1]); r[6] = f2bf(b[2]); r[7] = f2bf(b[3]);
  return r;
}

// ---------------- K0: W fp32 -> bf16 ----------------
__global__ void k0_pack(const float* __restrict__ W, short* __restrict__ Wbf) {
  int idx = blockIdx.x * 256 + threadIdx.x;
  f32x4 v = *(const f32x4*)(W + (size_t)idx * 4);
  bf16x4 pk;
  pk[0] = f2bf(v[0]); pk[1] = f2bf(v[1]); pk[2] = f2bf(v[2]); pk[3] = f2bf(v[3]);
  *(bf16x4*)(Wbf + (size_t)idx * 4) = pk;
}

// ---------------- K0b: domain uniformity check ----------------
__global__ void k0_check(const float* __restrict__ domain, float* __restrict__ flag) {
  __shared__ int s_ok[4];
  const int t = threadIdx.x;
  float v0 = domain[0];
  bool ok = true;
  for (int x = t; x < 72 * 72; x += 256) ok = ok && (domain[x] == v0);
  unsigned long long m = __ballot(ok);
  if ((t & 63) == 0) s_ok[t >> 6] = (m == ~0ull) ? 1 : 0;
  __syncthreads();
  if (t == 0) {
    flag[0] = v0;
    flag[1] = (s_ok[0] && s_ok[1] && s_ok[2] && s_ok[3]) ? 1.f : 0.f;
  }
}

// ---------------- k2a: pre-scaled weights, wave-per-row (R9-proven) ----------------
__global__ __launch_bounds__(256) void k2a_weights(
    const float* __restrict__ dist, const float* __restrict__ bear,
    const float* __restrict__ head, const float* __restrict__ seqmask,
    const float* __restrict__ domain, const float* __restrict__ uflag,
    short* __restrict__ weBuf) {
  __shared__ float sMask[256];
  const int t = threadIdx.x;
  const int b = blockIdx.x >> 3;
  const int i0 = (blockIdx.x & 7) * 32;
  if (t < 256) sMask[t] = seqmask[b * 256 + t];
  __syncthreads();

  const int w = t >> 6, l = t & 63;
  const int j0 = l * 4;
  const float dval = uflag[0];
  const bool  uni  = uflag[1] != 0.f;
  const f32x4 mj = *(const f32x4*)(sMask + j0);

  f32x4 dv[8];
  #pragma unroll
  for (int rr = 0; rr < 8; ++rr) {
    int i = i0 + w * 8 + rr;
    dv[rr] = *(const f32x4*)(dist + ((size_t)b * 256 + i) * 256 + j0);
  }

  #pragma unroll
  for (int rr = 0; rr < 8; ++rr) {
    const int i = i0 + w * 8 + rr;
    const float mI = sMask[i];
    const size_t base = ((size_t)b * 256 + i) * 256;
    float ev[4];
    float rs = 0.f;
    if (uni) {
      #pragma unroll
      for (int e = 0; e < 4; ++e) {
        float wv = fmaxf(dval - dv[rr][e], 0.f);
        bool valid = (i != j0 + e) && (mI != 0.f) && (mj[e] != 0.f);
        float ex = (wv > 0.f) ? __expf(wv) : 0.f;
        ex = valid ? ex : 0.f;
        rs += ex;
        ev[e] = valid ? (ex + EPSC) : 0.f;
      }
    } else {
      f32x4 bv = *(const f32x4*)(bear + base + j0);
      f32x4 hv = *(const f32x4*)(head + base + j0);
      #pragma unroll
      for (int e = 0; e < 4; ++e) {
        float f1 = fminf(fmaxf(floorf((hv[e] + 2.5f) * 0.2f), 0.f), 71.f);
        float f2 = fminf(fmaxf(floorf((bv[e] + 2.5f) * 0.2f), 0.f), 71.f);
        float wv = fmaxf(domain[(int)(f1 * 72.f + f2)] - dv[rr][e], 0.f);
        bool valid = (i != j0 + e) && (mI != 0.f) && (mj[e] != 0.f);
        float ex = (wv > 0.f) ? __expf(wv) : 0.f;
        ex = valid ? ex : 0.f;
        rs += ex;
        ev[e] = valid ? (ex + EPSC) : 0.f;
      }
    }
    rs += __shfl_xor(rs, 1, 64);
    rs += __shfl_xor(rs, 2, 64);
    rs += __shfl_xor(rs, 4, 64);
    rs += __shfl_xor(rs, 8, 64);
    rs += __shfl_xor(rs, 16, 64);
    rs += __shfl_xor(rs, 32, 64);
    const float scale = 1.0f / (rs + 257.0f * EPSC);
    bf16x4 pk;
    pk[0] = f2bf(ev[0] * scale); pk[1] = f2bf(ev[1] * scale);
    pk[2] = f2bf(ev[2] * scale); pk[3] = f2bf(ev[3] * scale);
    *(bf16x4*)(weBuf + base + j0) = pk;
  }
}

// ---------------- k1_p1t: P1T = (H W1^T)^T, k2b skeleton ----------------
// grid 1024 (XCD-swizzled), block 512, LDS 32768 -> 4 blocks/CU.
// 8 waves: wr=wid&3 (4 x 16 j-rows), wc=wid>>2 (2 x 128 d); acc[8].
// A = H rows per-thread (f32 -> bf16); B = W1 chunk via gload16 (swizzled).
__global__ __launch_bounds__(512) void k1_p1t(
    const float* __restrict__ H, const short* __restrict__ Wbf,
    short* __restrict__ P1T) {
  extern __shared__ char sm[];
  char* sB = sm;
  const int t = threadIdx.x;
  const int x = blockIdx.x;
  const int blk = (x & 7) * 128 + (x >> 3);    // bijective: 1024 = 8*128
  const int n0 = blk * 64;
  const int b  = n0 >> 8;
  const int jb = n0 & 255;

  const int wid = t >> 6, l = t & 63;
  const int lr = l & 15, lg = l >> 4;
  const int wr = wid & 3, wc = wid >> 2;
  const int r3 = l >> 3, sl = l & 7;
  const int sswz = (sl ^ r3) * 8;
  const int sw = (lr & 7) << 4;

  const size_t hbase = ((size_t)(n0 + wr * 16 + lr)) * 256;   // this thread's A row

  f32x4 acc[8] = {};

  for (int c = 0; c < 4; ++c) {
    const int kk = c * 64;
    #pragma unroll
    for (int p = 0; p < 4; ++p) {
      int dd = wid * 8 + r3 + 64 * p;
      gload16(Wbf + (size_t)dd * 512 + kk + sswz, sB + (wid * 8 + 64 * p) * 128);
    }
    __syncthreads();
    #pragma unroll
    for (int sub = 0; sub < 2; ++sub) {
      bf16x8 av = cvt8(H + hbase + kk + sub * 32 + lg * 8);
      #pragma unroll
      for (int n = 0; n < 8; ++n) {
        const int d = wc * 128 + n * 16 + lr;
        bf16x8 bb = *(const bf16x8*)(sB + d * 128 + ((sub * 64 + lg * 16) ^ sw));
        acc[n] = __builtin_amdgcn_mfma_f32_16x16x32_bf16(av, bb, acc[n], 0, 0, 0);
      }
    }
    __syncthreads();
  }

  // epilogue: transposed write P1T[b][d][jb + wr*16 + lg*4 + r]
  #pragma unroll
  for (int n = 0; n < 8; ++n) {
    const int d = wc * 128 + n * 16 + lr;
    f32x4 v = acc[n];
    bf16x4 pk;
    pk[0] = f2bf(v[0]); pk[1] = f2bf(v[1]); pk[2] = f2bf(v[2]); pk[3] = f2bf(v[3]);
    *(bf16x4*)(P1T + (size_t)b * 65536 + (size_t)d * 256 + jb + wr * 16 + lg * 4) = pk;
  }
}

// ---------------- k2b: out = weBuf @ P1T + bf16(H) @ W2 + bias, K=512 ----------------
// grid 1024 (XCD-swizzled), block 512, LDS 33792 -> 4 blocks/CU. 8 chunks:
// g=0..3: A = weBuf direct (bf16), B = P1T[b] gload16
// g=4..7: A = H per-thread cvt,   B = Wbf[:, 256+...] gload16
__global__ __launch_bounds__(512) void k2b_gemm(
    const short* __restrict__ weBuf, const short* __restrict__ P1T,
    const short* __restrict__ Wbf, const float* __restrict__ H,
    const float* __restrict__ bias, float* __restrict__ out) {
  extern __shared__ char sm[];
  char*  sB    = sm;
  float* sBias = (float*)(sm + 32768);
  const int t = threadIdx.x;
  const int x = blockIdx.x;
  const int blk = (x & 7) * 128 + (x >> 3);    // bijective: 1024 = 8*128
  const int b  = blk >> 2;
  const int i0 = (blk & 3) * 64;

  const int wid = t >> 6, l = t & 63;
  const int lr = l & 15, lg = l >> 4;
  const int wr = wid & 3, wc = wid >> 2;
  const int r3 = l >> 3, sl = l & 7;
  const int sswz = (sl ^ r3) * 8;
  const int sw = (lr & 7) << 4;

  const short* __restrict__ P1b = P1T + (size_t)b * 65536;
  const int i = i0 + wr * 16 + lr;
  const size_t abase = ((size_t)b * 256 + i) * 256;

  if (t < 256) sBias[t] = bias[t];

  f32x4 acc[8] = {};

  #pragma unroll 2
  for (int g = 0; g < 8; ++g) {
    const int kk = (g & 3) * 64;
    if (g < 4) {
      #pragma unroll
      for (int p = 0; p < 4; ++p) {
        int dd = wid * 8 + r3 + 64 * p;
        gload16(P1b + (size_t)dd * 256 + kk + sswz, sB + (wid * 8 + 64 * p) * 128);
      }
    } else {
      #pragma unroll
      for (int p = 0; p < 4; ++p) {
        int dd = wid * 8 + r3 + 64 * p;
        gload16(Wbf + (size_t)dd * 512 + 256 + kk + sswz, sB + (wid * 8 + 64 * p) * 128);
      }
    }
    __syncthreads();
    #pragma unroll
    for (int sub = 0; sub < 2; ++sub) {
      bf16x8 av;
      if (g < 4) av = *(const bf16x8*)(weBuf + abase + kk + sub * 32 + lg * 8);
      else       av = cvt8(H + abase + kk + sub * 32 + lg * 8);
      #pragma unroll
      for (int n = 0; n < 8; ++n) {
        const int d = wc * 128 + n * 16 + lr;
        bf16x8 bb = *(const bf16x8*)(sB + d * 128 + ((sub * 64 + lg * 16) ^ sw));
        acc[n] = __builtin_amdgcn_mfma_f32_16x16x32_bf16(av, bb, acc[n], 0, 0, 0);
      }
    }
    __syncthreads();
  }

  // epilogue: + bias, fp32 store
  #pragma unroll
  for (int n = 0; n < 8; ++n) {
    const int d = wc * 128 + n * 16 + lr;
    const float bs = sBias[d];
    #pragma unroll
    for (int r = 0; r < 4; ++r) {
      const int row = i0 + wr * 16 + lg * 4 + r;
      out[((size_t)b * 256 + row) * 256 + d] = acc[n][r] + bs;
    }
  }
}

extern "C" void kernel_launch(void* const* d_in, const int* in_sizes, int n_in,
                              void* d_out, int out_size, void* d_ws, size_t ws_size,
                              hipStream_t stream) {
  const float* hidden  = (const float*)d_in[0];
  const float* dist    = (const float*)d_in[1];
  const float* bear    = (const float*)d_in[2];
  const float* head    = (const float*)d_in[3];
  const float* seqmask = (const float*)d_in[4];
  const float* domain  = (const float*)d_in[5];
  const float* W       = (const float*)d_in[6];
  const float* bias    = (const float*)d_in[7];
  float* out = (float*)d_out;

  char* ws = (char*)d_ws;
  short* Wbf   = (short*)ws;                                 // 512 KB
  float* flag  = (float*)(ws + 524288);                      // 2 floats
  short* P1T   = (short*)(ws + (1u << 20));                  // 32 MB
  short* weBuf = (short*)(ws + (1u << 20) + (32u << 20));    // 32 MB

  k0_pack<<<128, 256, 0, stream>>>(W, Wbf);
  k0_check<<<1, 256, 0, stream>>>(domain, flag);
  k2a_weights<<<2048, 256, 0, stream>>>(dist, bear, head, seqmask, domain, flag, weBuf);
  k1_p1t<<<1024, 512, 32768, stream>>>(hidden, Wbf, P1T);
  k2b_gemm<<<1024, 512, 33792, stream>>>(weBuf, P1T, Wbf, hidden, bias, out);
}

// Round 15
// 114.202 us; speedup vs baseline: 1.1795x; 1.0067x over previous
//
#include <hip/hip_runtime.h>
#include <hip/hip_bf16.h>

// spatial_attention: out = weights @ (H W1^T) + H @ W2^T + bias
//   Domain uniform (runtime-verified) -> weights fast path: w = relu(dval - dist).
//   All GEMMs use the R10-proven skeleton: gload16 B-staging (linear dest +
//   pre-swizzled source + XOR reads), 64-row blocks, 8 waves (16r x 128d, acc[8]),
//   4 blocks/CU, XCD-swizzled grid.
//   K0    : Wbf = bf16(W); k0_check -> {dval, uniform}
//   k2a   : weights -> weBuf (pre-scaled bf16), wave-per-row, tiny LDS
//   k1_p1t: P1T[b][d][j] = bf16((H W1^T)^T), A=H per-thread cvt, B=W1 gload16
//   k2b   : out = weBuf @ P1T (chunks 0-3) + bf16(H) @ W2 (chunks 4-7) + bias
// Workspace: Wbf 512KB @0 ; flag @512KB ; P1T 32MB @1MB ; weBuf 32MB @33MB

typedef __attribute__((ext_vector_type(4))) float  f32x4;
typedef __attribute__((ext_vector_type(8))) short  bf16x8;
typedef __attribute__((ext_vector_type(4))) short  bf16x4;

#define EPSC 1e-14f

__device__ __forceinline__ short f2bf(float v) {
  __hip_bfloat16 h = __float2bfloat16(v);
  return *reinterpret_cast<short*>(&h);
}
__device__ __forceinline__ void gload16(const void* g, void* l) {
  __builtin_amdgcn_global_load_lds(
      (const __attribute__((address_space(1))) void*)g,
      (__attribute__((address_space(3))) void*)l, 16, 0, 0);
}
__device__ __forceinline__ bf16x8 cvt8(const float* p) {
  f32x4 a = *(const f32x4*)p;
  f32x4 b = *(const f32x4*)(p + 4);
  bf16x8 r;
  r[0] = f2bf(a[0]); r[1] = f2bf(a[1]); r[2] = f2bf(a[2]); r[3] = f2bf(a[3]);
  r[4] = f2bf(b[0]); r[5] = f2bf(b[1]); r[6] = f2bf(b[2]); r[7] = f2bf(b[3]);
  return r;
}

// ---------------- K0: W fp32 -> bf16 ----------------
__global__ void k0_pack(const float* __restrict__ W, short* __restrict__ Wbf) {
  int idx = blockIdx.x * 256 + threadIdx.x;
  f32x4 v = *(const f32x4*)(W + (size_t)idx * 4);
  bf16x4 pk;
  pk[0] = f2bf(v[0]); pk[1] = f2bf(v[1]); pk[2] = f2bf(v[2]); pk[3] = f2bf(v[3]);
  *(bf16x4*)(Wbf + (size_t)idx * 4) = pk;
}

// ---------------- K0b: domain uniformity check ----------------
__global__ void k0_check(const float* __restrict__ domain, float* __restrict__ flag) {
  __shared__ int s_ok[4];
  const int t = threadIdx.x;
  float v0 = domain[0];
  bool ok = true;
  for (int x = t; x < 72 * 72; x += 256) ok = ok && (domain[x] == v0);
  unsigned long long m = __ballot(ok);
  if ((t & 63) == 0) s_ok[t >> 6] = (m == ~0ull) ? 1 : 0;
  __syncthreads();
  if (t == 0) {
    flag[0] = v0;
    flag[1] = (s_ok[0] && s_ok[1] && s_ok[2] && s_ok[3]) ? 1.f : 0.f;
  }
}

// ---------------- k2a: pre-scaled weights, wave-per-row (R9-proven) ----------------
__global__ __launch_bounds__(256) void k2a_weights(
    const float* __restrict__ dist, const float* __restrict__ bear,
    const float* __restrict__ head, const float* __restrict__ seqmask,
    const float* __restrict__ domain, const float* __restrict__ uflag,
    short* __restrict__ weBuf) {
  __shared__ float sMask[256];
  const int t = threadIdx.x;
  const int b = blockIdx.x >> 3;
  const int i0 = (blockIdx.x & 7) * 32;
  if (t < 256) sMask[t] = seqmask[b * 256 + t];
  __syncthreads();

  const int w = t >> 6, l = t & 63;
  const int j0 = l * 4;
  const float dval = uflag[0];
  const bool  uni  = uflag[1] != 0.f;
  const f32x4 mj = *(const f32x4*)(sMask + j0);

  f32x4 dv[8];
  #pragma unroll
  for (int rr = 0; rr < 8; ++rr) {
    int i = i0 + w * 8 + rr;
    dv[rr] = *(const f32x4*)(dist + ((size_t)b * 256 + i) * 256 + j0);
  }

  #pragma unroll
  for (int rr = 0; rr < 8; ++rr) {
    const int i = i0 + w * 8 + rr;
    const float mI = sMask[i];
    const size_t base = ((size_t)b * 256 + i) * 256;
    float ev[4];
    float rs = 0.f;
    if (uni) {
      #pragma unroll
      for (int e = 0; e < 4; ++e) {
        float wv = fmaxf(dval - dv[rr][e], 0.f);
        bool valid = (i != j0 + e) && (mI != 0.f) && (mj[e] != 0.f);
        float ex = (wv > 0.f) ? __expf(wv) : 0.f;
        ex = valid ? ex : 0.f;
        rs += ex;
        ev[e] = valid ? (ex + EPSC) : 0.f;
      }
    } else {
      f32x4 bv = *(const f32x4*)(bear + base + j0);
      f32x4 hv = *(const f32x4*)(head + base + j0);
      #pragma unroll
      for (int e = 0; e < 4; ++e) {
        float f1 = fminf(fmaxf(floorf((hv[e] + 2.5f) * 0.2f), 0.f), 71.f);
        float f2 = fminf(fmaxf(floorf((bv[e] + 2.5f) * 0.2f), 0.f), 71.f);
        float wv = fmaxf(domain[(int)(f1 * 72.f + f2)] - dv[rr][e], 0.f);
        bool valid = (i != j0 + e) && (mI != 0.f) && (mj[e] != 0.f);
        float ex = (wv > 0.f) ? __expf(wv) : 0.f;
        ex = valid ? ex : 0.f;
        rs += ex;
        ev[e] = valid ? (ex + EPSC) : 0.f;
      }
    }
    rs += __shfl_xor(rs, 1, 64);
    rs += __shfl_xor(rs, 2, 64);
    rs += __shfl_xor(rs, 4, 64);
    rs += __shfl_xor(rs, 8, 64);
    rs += __shfl_xor(rs, 16, 64);
    rs += __shfl_xor(rs, 32, 64);
    const float scale = 1.0f / (rs + 257.0f * EPSC);
    bf16x4 pk;
    pk[0] = f2bf(ev[0] * scale); pk[1] = f2bf(ev[1] * scale);
    pk[2] = f2bf(ev[2] * scale); pk[3] = f2bf(ev[3] * scale);
    *(bf16x4*)(weBuf + base + j0) = pk;
  }
}

// ---------------- k1_p1t: P1T = (H W1^T)^T, k2b skeleton ----------------
// grid 1024 (XCD-swizzled), block 512, LDS 32768 -> 4 blocks/CU.
// 8 waves: wr=wid&3 (4 x 16 j-rows), wc=wid>>2 (2 x 128 d); acc[8].
// A = H rows per-thread (f32 -> bf16); B = W1 chunk via gload16 (swizzled).
__global__ __launch_bounds__(512) void k1_p1t(
    const float* __restrict__ H, const short* __restrict__ Wbf,
    short* __restrict__ P1T) {
  extern __shared__ char sm[];
  char* sB = sm;
  const int t = threadIdx.x;
  const int x = blockIdx.x;
  const int blk = (x & 7) * 128 + (x >> 3);    // bijective: 1024 = 8*128
  const int n0 = blk * 64;
  const int b  = n0 >> 8;
  const int jb = n0 & 255;

  const int wid = t >> 6, l = t & 63;
  const int lr = l & 15, lg = l >> 4;
  const int wr = wid & 3, wc = wid >> 2;
  const int r3 = l >> 3, sl = l & 7;
  const int sswz = (sl ^ r3) * 8;
  const int sw = (lr & 7) << 4;

  const size_t hbase = ((size_t)(n0 + wr * 16 + lr)) * 256;   // this thread's A row

  f32x4 acc[8] = {};

  for (int c = 0; c < 4; ++c) {
    const int kk = c * 64;
    #pragma unroll
    for (int p = 0; p < 4; ++p) {
      int dd = wid * 8 + r3 + 64 * p;
      gload16(Wbf + (size_t)dd * 512 + kk + sswz, sB + (wid * 8 + 64 * p) * 128);
    }
    __syncthreads();
    #pragma unroll
    for (int sub = 0; sub < 2; ++sub) {
      bf16x8 av = cvt8(H + hbase + kk + sub * 32 + lg * 8);
      #pragma unroll
      for (int n = 0; n < 8; ++n) {
        const int d = wc * 128 + n * 16 + lr;
        bf16x8 bb = *(const bf16x8*)(sB + d * 128 + ((sub * 64 + lg * 16) ^ sw));
        acc[n] = __builtin_amdgcn_mfma_f32_16x16x32_bf16(av, bb, acc[n], 0, 0, 0);
      }
    }
    __syncthreads();
  }

  // epilogue: transposed write P1T[b][d][jb + wr*16 + lg*4 + r]
  #pragma unroll
  for (int n = 0; n < 8; ++n) {
    const int d = wc * 128 + n * 16 + lr;
    f32x4 v = acc[n];
    bf16x4 pk;
    pk[0] = f2bf(v[0]); pk[1] = f2bf(v[1]); pk[2] = f2bf(v[2]); pk[3] = f2bf(v[3]);
    *(bf16x4*)(P1T + (size_t)b * 65536 + (size_t)d * 256 + jb + wr * 16 + lg * 4) = pk;
  }
}

// ---------------- k2b: out = weBuf @ P1T + bf16(H) @ W2 + bias, K=512 ----------------
// grid 1024 (XCD-swizzled), block 512, LDS 33792 -> 4 blocks/CU. 8 chunks:
// g=0..3: A = weBuf direct (bf16), B = P1T[b] gload16
// g=4..7: A = H per-thread cvt,   B = Wbf[:, 256+...] gload16
__global__ __launch_bounds__(512) void k2b_gemm(
    const short* __restrict__ weBuf, const short* __restrict__ P1T,
    const short* __restrict__ Wbf, const float* __restrict__ H,
    const float* __restrict__ bias, float* __restrict__ out) {
  extern __shared__ char sm[];
  char*  sB    = sm;
  float* sBias = (float*)(sm + 32768);
  const int t = threadIdx.x;
  const int x = blockIdx.x;
  const int blk = (x & 7) * 128 + (x >> 3);    // bijective: 1024 = 8*128
  const int b  = blk >> 2;
  const int i0 = (blk & 3) * 64;

  const int wid = t >> 6, l = t & 63;
  const int lr = l & 15, lg = l >> 4;
  const int wr = wid & 3, wc = wid >> 2;
  const int r3 = l >> 3, sl = l & 7;
  const int sswz = (sl ^ r3) * 8;
  const int sw = (lr & 7) << 4;

  const short* __restrict__ P1b = P1T + (size_t)b * 65536;
  const int i = i0 + wr * 16 + lr;
  const size_t abase = ((size_t)b * 256 + i) * 256;

  if (t < 256) sBias[t] = bias[t];

  f32x4 acc[8] = {};

  #pragma unroll 2
  for (int g = 0; g < 8; ++g) {
    const int kk = (g & 3) * 64;
    if (g < 4) {
      #pragma unroll
      for (int p = 0; p < 4; ++p) {
        int dd = wid * 8 + r3 + 64 * p;
        gload16(P1b + (size_t)dd * 256 + kk + sswz, sB + (wid * 8 + 64 * p) * 128);
      }
    } else {
      #pragma unroll
      for (int p = 0; p < 4; ++p) {
        int dd = wid * 8 + r3 + 64 * p;
        gload16(Wbf + (size_t)dd * 512 + 256 + kk + sswz, sB + (wid * 8 + 64 * p) * 128);
      }
    }
    __syncthreads();
    #pragma unroll
    for (int sub = 0; sub < 2; ++sub) {
      bf16x8 av;
      if (g < 4) av = *(const bf16x8*)(weBuf + abase + kk + sub * 32 + lg * 8);
      else       av = cvt8(H + abase + kk + sub * 32 + lg * 8);
      #pragma unroll
      for (int n = 0; n < 8; ++n) {
        const int d = wc * 128 + n * 16 + lr;
        bf16x8 bb = *(const bf16x8*)(sB + d * 128 + ((sub * 64 + lg * 16) ^ sw));
        acc[n] = __builtin_amdgcn_mfma_f32_16x16x32_bf16(av, bb, acc[n], 0, 0, 0);
      }
    }
    __syncthreads();
  }

  // epilogue: + bias, fp32 store
  #pragma unroll
  for (int n = 0; n < 8; ++n) {
    const int d = wc * 128 + n * 16 + lr;
    const float bs = sBias[d];
    #pragma unroll
    for (int r = 0; r < 4; ++r) {
      const int row = i0 + wr * 16 + lg * 4 + r;
      out[((size_t)b * 256 + row) * 256 + d] = acc[n][r] + bs;
    }
  }
}

extern "C" void kernel_launch(void* const* d_in, const int* in_sizes, int n_in,
                              void* d_out, int out_size, void* d_ws, size_t ws_size,
                              hipStream_t stream) {
  const float* hidden  = (const float*)d_in[0];
  const float* dist    = (const float*)d_in[1];
  const float* bear    = (const float*)d_in[2];
  const float* head    = (const float*)d_in[3];
  const float* seqmask = (const float*)d_in[4];
  const float* domain  = (const float*)d_in[5];
  const float* W       = (const float*)d_in[6];
  const float* bias    = (const float*)d_in[7];
  float* out = (float*)d_out;

  char* ws = (char*)d_ws;
  short* Wbf   = (short*)ws;                                 // 512 KB
  float* flag  = (float*)(ws + 524288);                      // 2 floats
  short* P1T   = (short*)(ws + (1u << 20));                  // 32 MB
  short* weBuf = (short*)(ws + (1u << 20) + (32u << 20));    // 32 MB

  k0_pack<<<128, 256, 0, stream>>>(W, Wbf);
  k0_check<<<1, 256, 0, stream>>>(domain, flag);
  k2a_weights<<<2048, 256, 0, stream>>>(dist, bear, head, seqmask, domain, flag, weBuf);
  k1_p1t<<<1024, 512, 32768, stream>>>(hidden, Wbf, P1T);
  k2b_gemm<<<1024, 512, 33792, stream>>>(weBuf, P1T, Wbf, hidden, bias, out);
}

// Round 16
// 112.357 us; speedup vs baseline: 1.1989x; 1.0164x over previous
//
#include <hip/hip_runtime.h>
#include <hip/hip_bf16.h>

// spatial_attention: out = weights @ (H W1^T) + H @ W2^T + bias
//   Domain uniform (runtime-verified) -> weights fast path: w = relu(dval - dist).
//   GEMM skeleton (R10-proven) + 2-PHASE DOUBLE-BUFFER (issue next-chunk
//   gload16 BEFORE current compute; one barrier per chunk -> loads fly under MFMA).
//   K0    : Wbf = bf16(W); k0_check -> {dval, uniform}
//   k2a   : weights -> weBuf (pre-scaled bf16), wave-per-row, tiny LDS
//   k1_p1t: P1T[b][d][j] = bf16((H W1^T)^T), dbuf 2x32KB
//   k2b   : out = weBuf @ P1T (g=0-3) + bf16(H) @ W2 (g=4-7) + bias, dbuf 2x32KB
// Workspace: Wbf 512KB @0 ; flag @512KB ; P1T 32MB @1MB ; weBuf 32MB @33MB

typedef __attribute__((ext_vector_type(4))) float  f32x4;
typedef __attribute__((ext_vector_type(8))) short  bf16x8;
typedef __attribute__((ext_vector_type(4))) short  bf16x4;

#define EPSC 1e-14f

__device__ __forceinline__ short f2bf(float v) {
  __hip_bfloat16 h = __float2bfloat16(v);
  return *reinterpret_cast<short*>(&h);
}
__device__ __forceinline__ void gload16(const void* g, void* l) {
  __builtin_amdgcn_global_load_lds(
      (const __attribute__((address_space(1))) void*)g,
      (__attribute__((address_space(3))) void*)l, 16, 0, 0);
}
__device__ __forceinline__ bf16x8 cvt8(const float* p) {
  f32x4 a = *(const f32x4*)p;
  f32x4 b = *(const f32x4*)(p + 4);
  bf16x8 r;
  r[0] = f2bf(a[0]); r[1] = f2bf(a[1]); r[2] = f2bf(a[2]); r[3] = f2bf(a[3]);
  r[4] = f2bf(b[0]); r[5] = f2bf(b[1]); r[6] = f2bf(b[2]); r[7] = f2bf(b[3]);
  return r;
}

// ---------------- K0: W fp32 -> bf16 ----------------
__global__ void k0_pack(const float* __restrict__ W, short* __restrict__ Wbf) {
  int idx = blockIdx.x * 256 + threadIdx.x;
  f32x4 v = *(const f32x4*)(W + (size_t)idx * 4);
  bf16x4 pk;
  pk[0] = f2bf(v[0]); pk[1] = f2bf(v[1]); pk[2] = f2bf(v[2]); pk[3] = f2bf(v[3]);
  *(bf16x4*)(Wbf + (size_t)idx * 4) = pk;
}

// ---------------- K0b: domain uniformity check ----------------
__global__ void k0_check(const float* __restrict__ domain, float* __restrict__ flag) {
  __shared__ int s_ok[4];
  const int t = threadIdx.x;
  float v0 = domain[0];
  bool ok = true;
  for (int x = t; x < 72 * 72; x += 256) ok = ok && (domain[x] == v0);
  unsigned long long m = __ballot(ok);
  if ((t & 63) == 0) s_ok[t >> 6] = (m == ~0ull) ? 1 : 0;
  __syncthreads();
  if (t == 0) {
    flag[0] = v0;
    flag[1] = (s_ok[0] && s_ok[1] && s_ok[2] && s_ok[3]) ? 1.f : 0.f;
  }
}

// ---------------- k2a: pre-scaled weights, wave-per-row (R9-proven) ----------------
__global__ __launch_bounds__(256) void k2a_weights(
    const float* __restrict__ dist, const float* __restrict__ bear,
    const float* __restrict__ head, const float* __restrict__ seqmask,
    const float* __restrict__ domain, const float* __restrict__ uflag,
    short* __restrict__ weBuf) {
  __shared__ float sMask[256];
  const int t = threadIdx.x;
  const int b = blockIdx.x >> 3;
  const int i0 = (blockIdx.x & 7) * 32;
  if (t < 256) sMask[t] = seqmask[b * 256 + t];
  __syncthreads();

  const int w = t >> 6, l = t & 63;
  const int j0 = l * 4;
  const float dval = uflag[0];
  const bool  uni  = uflag[1] != 0.f;
  const f32x4 mj = *(const f32x4*)(sMask + j0);

  f32x4 dv[8];
  #pragma unroll
  for (int rr = 0; rr < 8; ++rr) {
    int i = i0 + w * 8 + rr;
    dv[rr] = *(const f32x4*)(dist + ((size_t)b * 256 + i) * 256 + j0);
  }

  #pragma unroll
  for (int rr = 0; rr < 8; ++rr) {
    const int i = i0 + w * 8 + rr;
    const float mI = sMask[i];
    const size_t base = ((size_t)b * 256 + i) * 256;
    float ev[4];
    float rs = 0.f;
    if (uni) {
      #pragma unroll
      for (int e = 0; e < 4; ++e) {
        float wv = fmaxf(dval - dv[rr][e], 0.f);
        bool valid = (i != j0 + e) && (mI != 0.f) && (mj[e] != 0.f);
        float ex = (wv > 0.f) ? __expf(wv) : 0.f;
        ex = valid ? ex : 0.f;
        rs += ex;
        ev[e] = valid ? (ex + EPSC) : 0.f;
      }
    } else {
      f32x4 bv = *(const f32x4*)(bear + base + j0);
      f32x4 hv = *(const f32x4*)(head + base + j0);
      #pragma unroll
      for (int e = 0; e < 4; ++e) {
        float f1 = fminf(fmaxf(floorf((hv[e] + 2.5f) * 0.2f), 0.f), 71.f);
        float f2 = fminf(fmaxf(floorf((bv[e] + 2.5f) * 0.2f), 0.f), 71.f);
        float wv = fmaxf(domain[(int)(f1 * 72.f + f2)] - dv[rr][e], 0.f);
        bool valid = (i != j0 + e) && (mI != 0.f) && (mj[e] != 0.f);
        float ex = (wv > 0.f) ? __expf(wv) : 0.f;
        ex = valid ? ex : 0.f;
        rs += ex;
        ev[e] = valid ? (ex + EPSC) : 0.f;
      }
    }
    rs += __shfl_xor(rs, 1, 64);
    rs += __shfl_xor(rs, 2, 64);
    rs += __shfl_xor(rs, 4, 64);
    rs += __shfl_xor(rs, 8, 64);
    rs += __shfl_xor(rs, 16, 64);
    rs += __shfl_xor(rs, 32, 64);
    const float scale = 1.0f / (rs + 257.0f * EPSC);
    bf16x4 pk;
    pk[0] = f2bf(ev[0] * scale); pk[1] = f2bf(ev[1] * scale);
    pk[2] = f2bf(ev[2] * scale); pk[3] = f2bf(ev[3] * scale);
    *(bf16x4*)(weBuf + base + j0) = pk;
  }
}

// ---------------- k1_p1t: P1T = (H W1^T)^T, dbuf 2-phase ----------------
// grid 1024 (XCD-swizzled), block 512, LDS 65536 -> 2 blocks/CU.
__global__ __launch_bounds__(512) void k1_p1t(
    const float* __restrict__ H, const short* __restrict__ Wbf,
    short* __restrict__ P1T) {
  extern __shared__ char sm[];
  char* sB0 = sm;
  char* sB1 = sm + 32768;
  const int t = threadIdx.x;
  const int x = blockIdx.x;
  const int blk = (x & 7) * 128 + (x >> 3);    // bijective: 1024 = 8*128
  const int n0 = blk * 64;
  const int b  = n0 >> 8;
  const int jb = n0 & 255;

  const int wid = t >> 6, l = t & 63;
  const int lr = l & 15, lg = l >> 4;
  const int wr = wid & 3, wc = wid >> 2;
  const int r3 = l >> 3, sl = l & 7;
  const int sswz = (sl ^ r3) * 8;
  const int sw = (lr & 7) << 4;

  const size_t hbase = ((size_t)(n0 + wr * 16 + lr)) * 256;

  // prologue: stage chunk 0
  #pragma unroll
  for (int p = 0; p < 4; ++p) {
    int dd = wid * 8 + r3 + 64 * p;
    gload16(Wbf + (size_t)dd * 512 + sswz, sB0 + (wid * 8 + 64 * p) * 128);
  }
  __syncthreads();

  f32x4 acc[8] = {};

  #pragma unroll
  for (int c = 0; c < 4; ++c) {
    char* cur = (c & 1) ? sB1 : sB0;
    char* nxt = (c & 1) ? sB0 : sB1;
    if (c < 3) {                       // issue next chunk BEFORE compute
      #pragma unroll
      for (int p = 0; p < 4; ++p) {
        int dd = wid * 8 + r3 + 64 * p;
        gload16(Wbf + (size_t)dd * 512 + (c + 1) * 64 + sswz, nxt + (wid * 8 + 64 * p) * 128);
      }
    }
    const int kk = c * 64;
    #pragma unroll
    for (int sub = 0; sub < 2; ++sub) {
      bf16x8 av = cvt8(H + hbase + kk + sub * 32 + lg * 8);
      #pragma unroll
      for (int n = 0; n < 8; ++n) {
        const int d = wc * 128 + n * 16 + lr;
        bf16x8 bb = *(const bf16x8*)(cur + d * 128 + ((sub * 64 + lg * 16) ^ sw));
        acc[n] = __builtin_amdgcn_mfma_f32_16x16x32_bf16(av, bb, acc[n], 0, 0, 0);
      }
    }
    __syncthreads();                   // drains next-chunk loads (flew under MFMA)
  }

  // epilogue: transposed write
  #pragma unroll
  for (int n = 0; n < 8; ++n) {
    const int d = wc * 128 + n * 16 + lr;
    f32x4 v = acc[n];
    bf16x4 pk;
    pk[0] = f2bf(v[0]); pk[1] = f2bf(v[1]); pk[2] = f2bf(v[2]); pk[3] = f2bf(v[3]);
    *(bf16x4*)(P1T + (size_t)b * 65536 + (size_t)d * 256 + jb + wr * 16 + lg * 4) = pk;
  }
}

// ---------------- k2b: out = weBuf @ P1T + bf16(H) @ W2 + bias, K=512, dbuf ----------------
// grid 1024 (XCD-swizzled), block 512, LDS 66560 -> 2 blocks/CU. 8 chunks, 1 barrier each.
__global__ __launch_bounds__(512) void k2b_gemm(
    const short* __restrict__ weBuf, const short* __restrict__ P1T,
    const short* __restrict__ Wbf, const float* __restrict__ H,
    const float* __restrict__ bias, float* __restrict__ out) {
  extern __shared__ char sm[];
  char*  sB0   = sm;
  char*  sB1   = sm + 32768;
  float* sBias = (float*)(sm + 65536);
  const int t = threadIdx.x;
  const int x = blockIdx.x;
  const int blk = (x & 7) * 128 + (x >> 3);    // bijective: 1024 = 8*128
  const int b  = blk >> 2;
  const int i0 = (blk & 3) * 64;

  const int wid = t >> 6, l = t & 63;
  const int lr = l & 15, lg = l >> 4;
  const int wr = wid & 3, wc = wid >> 2;
  const int r3 = l >> 3, sl = l & 7;
  const int sswz = (sl ^ r3) * 8;
  const int sw = (lr & 7) << 4;

  const short* __restrict__ P1b = P1T + (size_t)b * 65536;
  const int i = i0 + wr * 16 + lr;
  const size_t abase = ((size_t)b * 256 + i) * 256;

  // prologue: stage chunk 0 (P1T kk=0) + bias
  #pragma unroll
  for (int p = 0; p < 4; ++p) {
    int dd = wid * 8 + r3 + 64 * p;
    gload16(P1b + (size_t)dd * 256 + sswz, sB0 + (wid * 8 + 64 * p) * 128);
  }
  if (t < 256) sBias[t] = bias[t];
  __syncthreads();

  f32x4 acc[8] = {};

  #pragma unroll
  for (int g = 0; g < 8; ++g) {
    char* cur = (g & 1) ? sB1 : sB0;
    char* nxt = (g & 1) ? sB0 : sB1;
    if (g < 7) {                       // issue next chunk BEFORE compute
      const int nk = ((g + 1) & 3) * 64;
      if (g + 1 < 4) {
        #pragma unroll
        for (int p = 0; p < 4; ++p) {
          int dd = wid * 8 + r3 + 64 * p;
          gload16(P1b + (size_t)dd * 256 + nk + sswz, nxt + (wid * 8 + 64 * p) * 128);
        }
      } else {
        #pragma unroll
        for (int p = 0; p < 4; ++p) {
          int dd = wid * 8 + r3 + 64 * p;
          gload16(Wbf + (size_t)dd * 512 + 256 + nk + sswz, nxt + (wid * 8 + 64 * p) * 128);
        }
      }
    }
    const int kk = (g & 3) * 64;
    #pragma unroll
    for (int sub = 0; sub < 2; ++sub) {
      bf16x8 av;
      if (g < 4) av = *(const bf16x8*)(weBuf + abase + kk + sub * 32 + lg * 8);
      else       av = cvt8(H + abase + kk + sub * 32 + lg * 8);
      #pragma unroll
      for (int n = 0; n < 8; ++n) {
        const int d = wc * 128 + n * 16 + lr;
        bf16x8 bb = *(const bf16x8*)(cur + d * 128 + ((sub * 64 + lg * 16) ^ sw));
        acc[n] = __builtin_amdgcn_mfma_f32_16x16x32_bf16(av, bb, acc[n], 0, 0, 0);
      }
    }
    __syncthreads();                   // drains next-chunk loads (flew under MFMA)
  }

  // epilogue: + bias, fp32 store
  #pragma unroll
  for (int n = 0; n < 8; ++n) {
    const int d = wc * 128 + n * 16 + lr;
    const float bs = sBias[d];
    #pragma unroll
    for (int r = 0; r < 4; ++r) {
      const int row = i0 + wr * 16 + lg * 4 + r;
      out[((size_t)b * 256 + row) * 256 + d] = acc[n][r] + bs;
    }
  }
}

extern "C" void kernel_launch(void* const* d_in, const int* in_sizes, int n_in,
                              void* d_out, int out_size, void* d_ws, size_t ws_size,
                              hipStream_t stream) {
  const float* hidden  = (const float*)d_in[0];
  const float* dist    = (const float*)d_in[1];
  const float* bear    = (const float*)d_in[2];
  const float* head    = (const float*)d_in[3];
  const float* seqmask = (const float*)d_in[4];
  const float* domain  = (const float*)d_in[5];
  const float* W       = (const float*)d_in[6];
  const float* bias    = (const float*)d_in[7];
  float* out = (float*)d_out;

  char* ws = (char*)d_ws;
  short* Wbf   = (short*)ws;                                 // 512 KB
  float* flag  = (float*)(ws + 524288);                      // 2 floats
  short* P1T   = (short*)(ws + (1u << 20));                  // 32 MB
  short* weBuf = (short*)(ws + (1u << 20) + (32u << 20));    // 32 MB

  k0_pack<<<128, 256, 0, stream>>>(W, Wbf);
  k0_check<<<1, 256, 0, stream>>>(domain, flag);
  k2a_weights<<<2048, 256, 0, stream>>>(dist, bear, head, seqmask, domain, flag, weBuf);
  k1_p1t<<<1024, 512, 65536, stream>>>(hidden, Wbf, P1T);
  k2b_gemm<<<1024, 512, 66560, stream>>>(weBuf, P1T, Wbf, hidden, bias, out);
}

// Round 17
// 107.196 us; speedup vs baseline: 1.2566x; 1.0481x over previous
//
#include <hip/hip_runtime.h>
#include <hip/hip_bf16.h>

// spatial_attention: out = weights @ (H W1^T) + H @ W2^T + bias
//   Domain uniform (runtime-verified) -> weights fast path: w = relu(dval - dist).
//   R16 finding: GEMM time is per-block-dominated (K=256 and K=512 both 47us).
//   -> FAT BLOCKS: 128-row tiles, grid 512 (one residency round, 2 blocks/CU),
//      wave = 32r x 128d (acc[2][8]), dbuf 2x32KB B-staging via gload16
//      (linear dest + pre-swizzled source + XOR reads), XCD-swizzled grid.
//   K0    : Wbf = bf16(W); k0_check -> {dval, uniform}
//   k2a   : weights -> weBuf (pre-scaled bf16), wave-per-row, tiny LDS
//   k1_p1t: P1T[b][d][j] = bf16((H W1^T)^T)
//   k2b   : out = weBuf @ P1T (g=0-3) + bf16(H) @ W2 (g=4-7) + bias
// Workspace: Wbf 512KB @0 ; flag @512KB ; P1T 32MB @1MB ; weBuf 32MB @33MB

typedef __attribute__((ext_vector_type(4))) float  f32x4;
typedef __attribute__((ext_vector_type(8))) short  bf16x8;
typedef __attribute__((ext_vector_type(4))) short  bf16x4;

#define EPSC 1e-14f

__device__ __forceinline__ short f2bf(float v) {
  __hip_bfloat16 h = __float2bfloat16(v);
  return *reinterpret_cast<short*>(&h);
}
__device__ __forceinline__ void gload16(const void* g, void* l) {
  __builtin_amdgcn_global_load_lds(
      (const __attribute__((address_space(1))) void*)g,
      (__attribute__((address_space(3))) void*)l, 16, 0, 0);
}
__device__ __forceinline__ bf16x8 cvt8(const float* p) {
  f32x4 a = *(const f32x4*)p;
  f32x4 b = *(const f32x4*)(p + 4);
  bf16x8 r;
  r[0] = f2bf(a[0]); r[1] = f2bf(a[1]); r[2] = f2bf(a[2]); r[3] = f2bf(a[3]);
  r[4] = f2bf(b[0]); r[5] = f2bf(b[1]); r[6] = f2bf(b[2]); r[7] = f2bf(b[3]);
  return r;
}

// ---------------- K0: W fp32 -> bf16 ----------------
__global__ void k0_pack(const float* __restrict__ W, short* __restrict__ Wbf) {
  int idx = blockIdx.x * 256 + threadIdx.x;
  f32x4 v = *(const f32x4*)(W + (size_t)idx * 4);
  bf16x4 pk;
  pk[0] = f2bf(v[0]); pk[1] = f2bf(v[1]); pk[2] = f2bf(v[2]); pk[3] = f2bf(v[3]);
  *(bf16x4*)(Wbf + (size_t)idx * 4) = pk;
}

// ---------------- K0b: domain uniformity check ----------------
__global__ void k0_check(const float* __restrict__ domain, float* __restrict__ flag) {
  __shared__ int s_ok[4];
  const int t = threadIdx.x;
  float v0 = domain[0];
  bool ok = true;
  for (int x = t; x < 72 * 72; x += 256) ok = ok && (domain[x] == v0);
  unsigned long long m = __ballot(ok);
  if ((t & 63) == 0) s_ok[t >> 6] = (m == ~0ull) ? 1 : 0;
  __syncthreads();
  if (t == 0) {
    flag[0] = v0;
    flag[1] = (s_ok[0] && s_ok[1] && s_ok[2] && s_ok[3]) ? 1.f : 0.f;
  }
}

// ---------------- k2a: pre-scaled weights, wave-per-row (R9-proven) ----------------
__global__ __launch_bounds__(256) void k2a_weights(
    const float* __restrict__ dist, const float* __restrict__ bear,
    const float* __restrict__ head, const float* __restrict__ seqmask,
    const float* __restrict__ domain, const float* __restrict__ uflag,
    short* __restrict__ weBuf) {
  __shared__ float sMask[256];
  const int t = threadIdx.x;
  const int b = blockIdx.x >> 3;
  const int i0 = (blockIdx.x & 7) * 32;
  if (t < 256) sMask[t] = seqmask[b * 256 + t];
  __syncthreads();

  const int w = t >> 6, l = t & 63;
  const int j0 = l * 4;
  const float dval = uflag[0];
  const bool  uni  = uflag[1] != 0.f;
  const f32x4 mj = *(const f32x4*)(sMask + j0);

  f32x4 dv[8];
  #pragma unroll
  for (int rr = 0; rr < 8; ++rr) {
    int i = i0 + w * 8 + rr;
    dv[rr] = *(const f32x4*)(dist + ((size_t)b * 256 + i) * 256 + j0);
  }

  #pragma unroll
  for (int rr = 0; rr < 8; ++rr) {
    const int i = i0 + w * 8 + rr;
    const float mI = sMask[i];
    const size_t base = ((size_t)b * 256 + i) * 256;
    float ev[4];
    float rs = 0.f;
    if (uni) {
      #pragma unroll
      for (int e = 0; e < 4; ++e) {
        float wv = fmaxf(dval - dv[rr][e], 0.f);
        bool valid = (i != j0 + e) && (mI != 0.f) && (mj[e] != 0.f);
        float ex = (wv > 0.f) ? __expf(wv) : 0.f;
        ex = valid ? ex : 0.f;
        rs += ex;
        ev[e] = valid ? (ex + EPSC) : 0.f;
      }
    } else {
      f32x4 bv = *(const f32x4*)(bear + base + j0);
      f32x4 hv = *(const f32x4*)(head + base + j0);
      #pragma unroll
      for (int e = 0; e < 4; ++e) {
        float f1 = fminf(fmaxf(floorf((hv[e] + 2.5f) * 0.2f), 0.f), 71.f);
        float f2 = fminf(fmaxf(floorf((bv[e] + 2.5f) * 0.2f), 0.f), 71.f);
        float wv = fmaxf(domain[(int)(f1 * 72.f + f2)] - dv[rr][e], 0.f);
        bool valid = (i != j0 + e) && (mI != 0.f) && (mj[e] != 0.f);
        float ex = (wv > 0.f) ? __expf(wv) : 0.f;
        ex = valid ? ex : 0.f;
        rs += ex;
        ev[e] = valid ? (ex + EPSC) : 0.f;
      }
    }
    rs += __shfl_xor(rs, 1, 64);
    rs += __shfl_xor(rs, 2, 64);
    rs += __shfl_xor(rs, 4, 64);
    rs += __shfl_xor(rs, 8, 64);
    rs += __shfl_xor(rs, 16, 64);
    rs += __shfl_xor(rs, 32, 64);
    const float scale = 1.0f / (rs + 257.0f * EPSC);
    bf16x4 pk;
    pk[0] = f2bf(ev[0] * scale); pk[1] = f2bf(ev[1] * scale);
    pk[2] = f2bf(ev[2] * scale); pk[3] = f2bf(ev[3] * scale);
    *(bf16x4*)(weBuf + base + j0) = pk;
  }
}

// ---------------- k1_p1t: P1T = (H W1^T)^T, FAT 128-row blocks, dbuf ----------------
// grid 512 (XCD-swizzled, 1 round), block 512, LDS 65536 -> 2 blocks/CU.
// waves: wr=wid&3 (4 x 32 rows), wc=wid>>2 (2 x 128 d); acc[2][8].
__global__ __launch_bounds__(512, 4) void k1_p1t(
    const float* __restrict__ H, const short* __restrict__ Wbf,
    short* __restrict__ P1T) {
  extern __shared__ char sm[];
  char* sB0 = sm;
  char* sB1 = sm + 32768;
  const int t = threadIdx.x;
  const int x = blockIdx.x;
  const int blk = (x & 7) * 64 + (x >> 3);     // bijective: 512 = 8*64
  const int n0 = blk * 128;
  const int b  = n0 >> 8;
  const int jb = n0 & 255;

  const int wid = t >> 6, l = t & 63;
  const int lr = l & 15, lg = l >> 4;
  const int wr = wid & 3, wc = wid >> 2;
  const int r3 = l >> 3, sl = l & 7;
  const int sswz = (sl ^ r3) * 8;
  const int sw = (lr & 7) << 4;

  const size_t h0 = ((size_t)(n0 + wr * 32 + lr)) * 256;
  const size_t h1 = h0 + 16 * 256;

  // prologue: stage chunk 0
  #pragma unroll
  for (int p = 0; p < 4; ++p) {
    int dd = wid * 8 + r3 + 64 * p;
    gload16(Wbf + (size_t)dd * 512 + sswz, sB0 + (wid * 8 + 64 * p) * 128);
  }
  __syncthreads();

  f32x4 acc[2][8] = {};

  #pragma unroll
  for (int c = 0; c < 4; ++c) {
    char* cur = (c & 1) ? sB1 : sB0;
    char* nxt = (c & 1) ? sB0 : sB1;
    if (c < 3) {                       // issue next chunk BEFORE compute
      #pragma unroll
      for (int p = 0; p < 4; ++p) {
        int dd = wid * 8 + r3 + 64 * p;
        gload16(Wbf + (size_t)dd * 512 + (c + 1) * 64 + sswz, nxt + (wid * 8 + 64 * p) * 128);
      }
    }
    const int kk = c * 64;
    #pragma unroll
    for (int sub = 0; sub < 2; ++sub) {
      bf16x8 av0 = cvt8(H + h0 + kk + sub * 32 + lg * 8);
      bf16x8 av1 = cvt8(H + h1 + kk + sub * 32 + lg * 8);
      #pragma unroll
      for (int n = 0; n < 8; ++n) {
        const int d = wc * 128 + n * 16 + lr;
        bf16x8 bb = *(const bf16x8*)(cur + d * 128 + ((sub * 64 + lg * 16) ^ sw));
        acc[0][n] = __builtin_amdgcn_mfma_f32_16x16x32_bf16(av0, bb, acc[0][n], 0, 0, 0);
        acc[1][n] = __builtin_amdgcn_mfma_f32_16x16x32_bf16(av1, bb, acc[1][n], 0, 0, 0);
      }
    }
    __syncthreads();
  }

  // epilogue: transposed write P1T[b][d][jb + wr*32 + m*16 + lg*4 + r]
  #pragma unroll
  for (int m = 0; m < 2; ++m) {
    #pragma unroll
    for (int n = 0; n < 8; ++n) {
      const int d = wc * 128 + n * 16 + lr;
      f32x4 v = acc[m][n];
      bf16x4 pk;
      pk[0] = f2bf(v[0]); pk[1] = f2bf(v[1]); pk[2] = f2bf(v[2]); pk[3] = f2bf(v[3]);
      *(bf16x4*)(P1T + (size_t)b * 65536 + (size_t)d * 256 + jb + wr * 32 + m * 16 + lg * 4) = pk;
    }
  }
}

// ---------------- k2b: out = weBuf @ P1T + bf16(H) @ W2 + bias, FAT blocks, dbuf ----------------
// grid 512 (XCD-swizzled, 1 round), block 512, LDS 66560 -> 2 blocks/CU. 8 chunks.
__global__ __launch_bounds__(512, 4) void k2b_gemm(
    const short* __restrict__ weBuf, const short* __restrict__ P1T,
    const short* __restrict__ Wbf, const float* __restrict__ H,
    const float* __restrict__ bias, float* __restrict__ out) {
  extern __shared__ char sm[];
  char*  sB0   = sm;
  char*  sB1   = sm + 32768;
  float* sBias = (float*)(sm + 65536);
  const int t = threadIdx.x;
  const int x = blockIdx.x;
  const int blk = (x & 7) * 64 + (x >> 3);     // bijective: 512 = 8*64
  const int b  = blk >> 1;
  const int i0 = (blk & 1) * 128;

  const int wid = t >> 6, l = t & 63;
  const int lr = l & 15, lg = l >> 4;
  const int wr = wid & 3, wc = wid >> 2;
  const int r3 = l >> 3, sl = l & 7;
  const int sswz = (sl ^ r3) * 8;
  const int sw = (lr & 7) << 4;

  const short* __restrict__ P1b = P1T + (size_t)b * 65536;
  const size_t a0 = ((size_t)b * 256 + i0 + wr * 32 + lr) * 256;
  const size_t a1 = a0 + 16 * 256;

  // prologue: stage chunk 0 (P1T kk=0) + bias
  #pragma unroll
  for (int p = 0; p < 4; ++p) {
    int dd = wid * 8 + r3 + 64 * p;
    gload16(P1b + (size_t)dd * 256 + sswz, sB0 + (wid * 8 + 64 * p) * 128);
  }
  if (t < 256) sBias[t] = bias[t];
  __syncthreads();

  f32x4 acc[2][8] = {};

  #pragma unroll
  for (int g = 0; g < 8; ++g) {
    char* cur = (g & 1) ? sB1 : sB0;
    char* nxt = (g & 1) ? sB0 : sB1;
    if (g < 7) {                       // issue next chunk BEFORE compute
      const int nk = ((g + 1) & 3) * 64;
      if (g + 1 < 4) {
        #pragma unroll
        for (int p = 0; p < 4; ++p) {
          int dd = wid * 8 + r3 + 64 * p;
          gload16(P1b + (size_t)dd * 256 + nk + sswz, nxt + (wid * 8 + 64 * p) * 128);
        }
      } else {
        #pragma unroll
        for (int p = 0; p < 4; ++p) {
          int dd = wid * 8 + r3 + 64 * p;
          gload16(Wbf + (size_t)dd * 512 + 256 + nk + sswz, nxt + (wid * 8 + 64 * p) * 128);
        }
      }
    }
    const int kk = (g & 3) * 64;
    #pragma unroll
    for (int sub = 0; sub < 2; ++sub) {
      bf16x8 av0, av1;
      if (g < 4) {
        av0 = *(const bf16x8*)(weBuf + a0 + kk + sub * 32 + lg * 8);
        av1 = *(const bf16x8*)(weBuf + a1 + kk + sub * 32 + lg * 8);
      } else {
        av0 = cvt8(H + a0 + kk + sub * 32 + lg * 8);
        av1 = cvt8(H + a1 + kk + sub * 32 + lg * 8);
      }
      #pragma unroll
      for (int n = 0; n < 8; ++n) {
        const int d = wc * 128 + n * 16 + lr;
        bf16x8 bb = *(const bf16x8*)(cur + d * 128 + ((sub * 64 + lg * 16) ^ sw));
        acc[0][n] = __builtin_amdgcn_mfma_f32_16x16x32_bf16(av0, bb, acc[0][n], 0, 0, 0);
        acc[1][n] = __builtin_amdgcn_mfma_f32_16x16x32_bf16(av1, bb, acc[1][n], 0, 0, 0);
      }
    }
    __syncthreads();
  }

  // epilogue: + bias, fp32 store
  #pragma unroll
  for (int m = 0; m < 2; ++m) {
    #pragma unroll
    for (int n = 0; n < 8; ++n) {
      const int d = wc * 128 + n * 16 + lr;
      const float bs = sBias[d];
      #pragma unroll
      for (int r = 0; r < 4; ++r) {
        const int row = i0 + wr * 32 + m * 16 + lg * 4 + r;
        out[((size_t)b * 256 + row) * 256 + d] = acc[m][n][r] + bs;
      }
    }
  }
}

extern "C" void kernel_launch(void* const* d_in, const int* in_sizes, int n_in,
                              void* d_out, int out_size, void* d_ws, size_t ws_size,
                              hipStream_t stream) {
  const float* hidden  = (const float*)d_in[0];
  const float* dist    = (const float*)d_in[1];
  const float* bear    = (const float*)d_in[2];
  const float* head    = (const float*)d_in[3];
  const float* seqmask = (const float*)d_in[4];
  const float* domain  = (const float*)d_in[5];
  const float* W       = (const float*)d_in[6];
  const float* bias    = (const float*)d_in[7];
  float* out = (float*)d_out;

  char* ws = (char*)d_ws;
  short* Wbf   = (short*)ws;                                 // 512 KB
  float* flag  = (float*)(ws + 524288);                      // 2 floats
  short* P1T   = (short*)(ws + (1u << 20));                  // 32 MB
  short* weBuf = (short*)(ws + (1u << 20) + (32u << 20));    // 32 MB

  k0_pack<<<128, 256, 0, stream>>>(W, Wbf);
  k0_check<<<1, 256, 0, stream>>>(domain, flag);
  k2a_weights<<<2048, 256, 0, stream>>>(dist, bear, head, seqmask, domain, flag, weBuf);
  k1_p1t<<<512, 512, 65536, stream>>>(hidden, Wbf, P1T);
  k2b_gemm<<<512, 512, 66560, stream>>>(weBuf, P1T, Wbf, hidden, bias, out);
}